// Round 8
// baseline (121.917 us; speedup 1.0000x reference)
//
#include <hip/hip_runtime.h>

#define NEG_INF (-1e30f)

typedef __bf16 bf16x8 __attribute__((ext_vector_type(8)));
typedef float  f32x4  __attribute__((ext_vector_type(4)));
typedef unsigned short ushort;

__device__ __forceinline__ float fast_tanhf(float x) {
    float e = __expf(2.0f * x);
    return 1.0f - 2.0f * __builtin_amdgcn_rcpf(1.0f + e);
}

__device__ __forceinline__ ushort f2bf(float f) {
    union { float f; unsigned u; } v; v.f = f;
    unsigned r = v.u + 0x7fffu + ((v.u >> 16) & 1u);   // RNE
    return (ushort)(r >> 16);
}

// async global->LDS, 16B/lane, LDS dest = wave-uniform base + lane*16
__device__ __forceinline__ void gload_lds16(const void* gsrc, void* ldsdst) {
    __builtin_amdgcn_global_load_lds(
        (const __attribute__((address_space(1))) unsigned int*)gsrc,
        (__attribute__((address_space(3))) unsigned int*)ldsdst, 16, 0, 0);
}

// ---------------------------------------------------------------------------
// K0: W_sa [H=512][C=512] fp32 -> Wt [C][H] bf16 (transposed)
// ---------------------------------------------------------------------------
__global__ void convw_kernel(const float* __restrict__ W, ushort* __restrict__ Wt) {
    int i = blockIdx.x * 256 + threadIdx.x;
    int h = i >> 9, c = i & 511;
    Wt[c * 512 + h] = f2bf(W[i]);
}

// ---------------------------------------------------------------------------
// K1: B-resident GEMM (R7 structure) + explicit DEPTH-2 A prefetch.
// 512 thr / 8 waves; block = 256 M-rows x 128 cols; B half-panel (64 KB) in
// LDS per pass; K loop is barrier-free. A-loads for step s+2 are issued at
// step s via a static 4-slot register rotation (all indices compile-time),
// so each wave hides ~2 steps of L2/L3 latency; prefetch runs straight
// through the pass boundary (A k-addresses are continuous).
// ---------------------------------------------------------------------------
__global__ __launch_bounds__(512) void gemm_scores_kernel(
    const float* __restrict__ feat, const ushort* __restrict__ Wt,
    const float* __restrict__ b_sa, const float* __restrict__ w_sc,
    float* __restrict__ sp) {

    __shared__ ushort Blds[32768];   // 64 KB: [kl 8][cf 8][kg 4][lr 16][8]

    const int tid  = threadIdx.x;
    const int wv   = tid >> 6;
    const int lane = tid & 63;
    const int lr   = lane & 15;
    const int kg   = lane >> 4;

    const int id   = blockIdx.x;
    const int g    = id & 7;
    const int loc  = id >> 3;
    const int msuper = g * 32 + (loc >> 2);   // 0..255
    const int by   = loc & 3;                 // 0..3
    const int m0   = msuper * 256;
    const int n0   = by * 128;
    const int mw   = m0 + wv * 32;            // this wave's 32 rows

    const float*  ag0  = feat + (size_t)(mw + lr) * 512 + kg * 8;
    const float*  ag1  = ag0 + 16 * 512;
    const ushort* bsrc = Wt + (size_t)(n0 + wv * 16 + lr) * 512 + kg * 8;

    f32x4 acc[2][8];
#pragma unroll
    for (int gr = 0; gr < 2; ++gr)
#pragma unroll
        for (int cf = 0; cf < 8; ++cf) acc[gr][cf] = (f32x4){0.f, 0.f, 0.f, 0.f};

    float4 q[4][4];   // rotation slot = step & 3 (static after unroll)
#define LOADQ(slot, s_)                                                      \
    {                                                                        \
        q[slot][0] = *reinterpret_cast<const float4*>(ag0 + (s_) * 32);      \
        q[slot][1] = *reinterpret_cast<const float4*>(ag0 + (s_) * 32 + 4);  \
        q[slot][2] = *reinterpret_cast<const float4*>(ag1 + (s_) * 32);      \
        q[slot][3] = *reinterpret_cast<const float4*>(ag1 + (s_) * 32 + 4);  \
    }

    LOADQ(0, 0)
    LOADQ(1, 1)

#pragma unroll
    for (int pass = 0; pass < 2; ++pass) {
        if (pass) __syncthreads();   // all waves done reading Blds(pass 0)
#pragma unroll
        for (int r = 0; r < 8; ++r)
            gload_lds16(bsrc + pass * 256 + r * 32,
                        (char*)Blds + r * 8192 + wv * 1024);
        __syncthreads();             // drains vmcnt: B resident (A prefetch also
                                     // drained here - already long in flight)

#pragma unroll
        for (int kl = 0; kl < 8; ++kl) {
            const int s = pass * 8 + kl;          // compile-time
            if (s + 2 < 16) LOADQ((s + 2) & 3, s + 2)   // depth-2 prefetch

            const float4* qc = q[s & 3];
            bf16x8 a0, a1;
            a0[0] = (__bf16)qc[0].x; a0[1] = (__bf16)qc[0].y; a0[2] = (__bf16)qc[0].z; a0[3] = (__bf16)qc[0].w;
            a0[4] = (__bf16)qc[1].x; a0[5] = (__bf16)qc[1].y; a0[6] = (__bf16)qc[1].z; a0[7] = (__bf16)qc[1].w;
            a1[0] = (__bf16)qc[2].x; a1[1] = (__bf16)qc[2].y; a1[2] = (__bf16)qc[2].z; a1[3] = (__bf16)qc[2].w;
            a1[4] = (__bf16)qc[3].x; a1[5] = (__bf16)qc[3].y; a1[6] = (__bf16)qc[3].z; a1[7] = (__bf16)qc[3].w;
#pragma unroll
            for (int cf = 0; cf < 8; ++cf) {
                const bf16x8 bf = *reinterpret_cast<const bf16x8*>(
                    (const char*)Blds + kl * 8192 + cf * 1024 + kg * 256 + lr * 16);
                acc[0][cf] = __builtin_amdgcn_mfma_f32_16x16x32_bf16(a0, bf, acc[0][cf], 0, 0, 0);
                acc[1][cf] = __builtin_amdgcn_mfma_f32_16x16x32_bf16(a1, bf, acc[1][cf], 0, 0, 0);
            }
        }
    }
#undef LOADQ

    // ---- wave-local epilogue: rsum over 128 cols of tanh(C+b_sa)*w_sc ----
    float rs[2][4];
#pragma unroll
    for (int gr = 0; gr < 2; ++gr)
#pragma unroll
        for (int r = 0; r < 4; ++r) rs[gr][r] = 0.0f;

#pragma unroll
    for (int cf = 0; cf < 8; ++cf) {
        const int col = n0 + cf * 16 + lr;
        const float w = w_sc[col];
        const float b = b_sa[col];
#pragma unroll
        for (int gr = 0; gr < 2; ++gr)
#pragma unroll
            for (int r = 0; r < 4; ++r)
                rs[gr][r] += fast_tanhf(acc[gr][cf][r] + b) * w;
    }
#pragma unroll
    for (int gr = 0; gr < 2; ++gr)
#pragma unroll
        for (int r = 0; r < 4; ++r) {
            float v = rs[gr][r];
            v += __shfl_xor(v, 1);
            v += __shfl_xor(v, 2);
            v += __shfl_xor(v, 4);
            v += __shfl_xor(v, 8);
            rs[gr][r] = v;
        }
    if (lr == 0) {
#pragma unroll
        for (int gr = 0; gr < 2; ++gr)
#pragma unroll
            for (int r = 0; r < 4; ++r)
                sp[(size_t)by * 65536 + mw + gr * 16 + kg * 4 + r] = rs[gr][r];
    }
}

// ---------------------------------------------------------------------------
// K2: combine 4 partials + b_sc + mask, per-batch masked softmax -> probs
// ---------------------------------------------------------------------------
__global__ void softmax_kernel(const float* __restrict__ sp, const float* __restrict__ b_sc,
                               const int* __restrict__ mask, float* __restrict__ probs) {
    int b = blockIdx.x, t = threadIdx.x;
    int i0 = b * 512 + t, i1 = i0 + 256;
    float s0 = sp[i0] + sp[65536 + i0] + sp[131072 + i0] + sp[196608 + i0] + b_sc[0];
    float s1 = sp[i1] + sp[65536 + i1] + sp[131072 + i1] + sp[196608 + i1] + b_sc[0];
    if (!mask[i0]) s0 = NEG_INF;
    if (!mask[i1]) s1 = NEG_INF;
    float m = fmaxf(s0, s1);
#pragma unroll
    for (int o = 1; o < 64; o <<= 1) m = fmaxf(m, __shfl_xor(m, o));
    __shared__ float red[4];
    if ((t & 63) == 0) red[t >> 6] = m;
    __syncthreads();
    m = fmaxf(fmaxf(red[0], red[1]), fmaxf(red[2], red[3]));
    float e0 = __expf(s0 - m), e1 = __expf(s1 - m);
    float z = e0 + e1;
#pragma unroll
    for (int o = 1; o < 64; o <<= 1) z += __shfl_xor(z, o);
    __syncthreads();
    if ((t & 63) == 0) red[t >> 6] = z;
    __syncthreads();
    float inv = 1.0f / (red[0] + red[1] + red[2] + red[3]);
    probs[i0] = e0 * inv;
    probs[i1] = e1 * inv;
}

// ---------------------------------------------------------------------------
// K3: pooled partial: block (b, c): rows [c*128, c*128+128), float4 cols
// ---------------------------------------------------------------------------
__global__ void pool_kernel(const float* __restrict__ feat,
                            const float* __restrict__ probs,
                            float* __restrict__ part) {
    int b = blockIdx.x, c = blockIdx.y, t = threadIdx.x;
    __shared__ float pl[128];
    __shared__ float red2[2][512];
    if (t < 128) pl[t] = probs[b * 512 + c * 128 + t];
    __syncthreads();
    int col4 = (t & 127) * 4;
    int stripe = t >> 7;
    const float* fb = feat + ((size_t)(b * 512 + c * 128 + stripe * 64)) * 512 + col4;
    float4 a4 = {0.f, 0.f, 0.f, 0.f};
#pragma unroll 8
    for (int n = 0; n < 64; ++n) {
        float p = pl[stripe * 64 + n];
        const float4 f4 = *reinterpret_cast<const float4*>(fb + (size_t)n * 512);
        a4.x = fmaf(p, f4.x, a4.x);
        a4.y = fmaf(p, f4.y, a4.y);
        a4.z = fmaf(p, f4.z, a4.z);
        a4.w = fmaf(p, f4.w, a4.w);
    }
    *reinterpret_cast<float4*>(&red2[stripe][col4]) = a4;
    __syncthreads();
    float x0 = red2[0][t] + red2[1][t];
    float x1 = red2[0][t + 256] + red2[1][t + 256];
    part[(size_t)c * 65536 + b * 512 + t]       = x0;
    part[(size_t)c * 65536 + b * 512 + t + 256] = x1;
}

// ---------------------------------------------------------------------------
// K4: out = tanh(sum of 4 partials)
// ---------------------------------------------------------------------------
__global__ void finish_kernel(const float* __restrict__ part, float* __restrict__ out) {
    int i = blockIdx.x * 256 + threadIdx.x;
    float s = part[i] + part[65536 + i] + part[131072 + i] + part[196608 + i];
    out[i] = fast_tanhf(s);
}

extern "C" void kernel_launch(void* const* d_in, const int* in_sizes, int n_in,
                              void* d_out, int out_size, void* d_ws, size_t ws_size,
                              hipStream_t stream) {
    const float* feat = (const float*)d_in[0];
    const int*   mask = (const int*)d_in[1];
    const float* W_sa = (const float*)d_in[2];
    const float* b_sa = (const float*)d_in[3];
    const float* w_sc = (const float*)d_in[4];
    const float* b_sc = (const float*)d_in[5];
    float* out = (float*)d_out;

    char* ws = (char*)d_ws;
    ushort* Wt    = (ushort*)ws;                               // 512 KB
    float*  sp    = (float*)(ws + (512 << 10));                // 1 MB (4 x 65536)
    float*  probs = (float*)(ws + (512 << 10) + (1024 << 10)); // 256 KB
    float*  part  = (float*)(ws + (512 << 10) + (1280 << 10)); // 1 MB (4 x 65536)

    hipLaunchKernelGGL(convw_kernel, dim3(1024), dim3(256), 0, stream, W_sa, Wt);
    hipLaunchKernelGGL(gemm_scores_kernel, dim3(1024), dim3(512), 0, stream,
                       feat, Wt, b_sa, w_sc, sp);
    hipLaunchKernelGGL(softmax_kernel, dim3(128), dim3(256), 0, stream,
                       sp, b_sc, mask, probs);
    hipLaunchKernelGGL(pool_kernel, dim3(128, 4), dim3(256), 0, stream, feat, probs, part);
    hipLaunchKernelGGL(finish_kernel, dim3(256), dim3(256), 0, stream, part, out);
}